// Round 1
// baseline (263.929 us; speedup 1.0000x reference)
//
#include <hip/hip_runtime.h>
#include <cstdint>
#include <cstddef>

// CombinedLoss: ALPHA*CE + BETA*Lovasz + GAMMA*Dice
// Shapes fixed by setup_inputs(): logits [8,20,131072] f32, target [8,131072] int
#define ALPHA_W 1.0f
#define BETA_W  1.0f
#define GAMMA_W 0.5f
#define EPS_V   1e-6f

constexpr int B = 8;
constexpr int C = 20;
constexpr int N = 131072;    // 2^17
constexpr int LOG2N = 17;

constexpr int NB  = 4096;    // Lovasz histogram buckets; |error| <= 1/NB
constexpr int K2T = 1024;    // threads per lovasz workgroup
constexpr int PER = NB / K2T;

// workspace layout
constexpr size_t CE_OFF   = 0;                      // double
constexpr size_t LOSS_OFF = 64;                     // float[B*C]
constexpr size_t DICE_OFF = LOSS_OFF + (size_t)B * C * sizeof(float);
constexpr size_t PRES_OFF = DICE_OFF + (size_t)B * C * sizeof(float);
constexpr size_t ERR_OFF  = 4096;                   // float[B*C*N], sign bit = fg
constexpr size_t ERR_BYTES = (size_t)B * C * N * sizeof(float);

// ---------------------------------------------------------------------------
// Kernel 1: per-(b,n) softmax over C. CE accumulation; optionally write the
// per-class error e = fg ? 1-p : p with fg packed into the sign bit.
// ---------------------------------------------------------------------------
template<bool WRITE_ERR>
__global__ __launch_bounds__(256) void ce_kernel(const float* __restrict__ logits,
                                                 const int*   __restrict__ target,
                                                 double*      __restrict__ ce_sum,
                                                 float*       __restrict__ err)
{
    const int tid = threadIdx.x;
    const int idx = blockIdx.x * 256 + tid;          // 0 .. B*N-1 (grid exact)
    const int b = idx >> LOG2N;
    const int n = idx & (N - 1);
    const float* lp = logits + ((size_t)b * C) * N + n;

    float t[C];
    float m = -1e30f;
#pragma unroll
    for (int k = 0; k < C; ++k) {
        t[k] = lp[(size_t)k * N];
        m = fmaxf(m, t[k]);
    }
    const int tg = target[idx];
    float lt = 0.f;
    float s = 0.f;
#pragma unroll
    for (int k = 0; k < C; ++k) {
        if (k == tg) lt = t[k];
        t[k] = __expf(t[k] - m);
        s += t[k];
    }
    const float nll = m + __logf(s) - lt;            // -log softmax[target]

    if constexpr (WRITE_ERR) {
        const float inv = 1.f / s;
        float* ep = err + ((size_t)b * C) * N + n;
#pragma unroll
        for (int k = 0; k < C; ++k) {
            const float p = t[k] * inv;
            const bool fg = (k == tg);
            const float e = fg ? (1.f - p) : p;      // e in [0,1]
            unsigned int bits = __float_as_uint(e) | (fg ? 0x80000000u : 0u);
            ep[(size_t)k * N] = __uint_as_float(bits);
        }
    }

    // block reduce CE then one double atomic per block
    __shared__ float red[256];
    red[tid] = nll;
    __syncthreads();
    for (int s2 = 128; s2 > 0; s2 >>= 1) {
        if (tid < s2) red[tid] += red[tid + s2];
        __syncthreads();
    }
    if (tid == 0) atomicAdd(ce_sum, (double)red[0]);
}

// ---------------------------------------------------------------------------
// Kernel 2: one workgroup per (b,c). Build an LDS histogram of errors
// (separately for fg/bg: counts and sums), suffix-scan counts in descending
// bucket order, then apply the closed-form telescoped Lovasz gradient per
// bucket. Dice numerator/denominator derive from the same sums.
//   fg block (U const):  contrib += sum_e_fg / U0
//   bg block (I const):  contrib += sum_e_bg * I1 / (U0*(U0+cnt_bg))
// ---------------------------------------------------------------------------
template<bool FROM_ERR>
__global__ __launch_bounds__(K2T) void lovasz_kernel(const float* __restrict__ err,
                                                     const float* __restrict__ logits,
                                                     const int*   __restrict__ target,
                                                     float* __restrict__ loss_bc,
                                                     float* __restrict__ dice_bc,
                                                     int*   __restrict__ present)
{
    __shared__ unsigned int s_cfg[NB];
    __shared__ unsigned int s_cbg[NB];
    __shared__ float s_sfg[NB];
    __shared__ float s_sbg[NB];
    __shared__ unsigned long long s_scan[K2T];
    __shared__ float s_red[3];

    const int bc = blockIdx.x;     // b*C + c
    const int b  = bc / C;
    const int c  = bc % C;
    const int tid = threadIdx.x;

    for (int i = tid; i < NB; i += K2T) {
        s_cfg[i] = 0u; s_cbg[i] = 0u; s_sfg[i] = 0.f; s_sbg[i] = 0.f;
    }
    if (tid < 3) s_red[tid] = 0.f;
    __syncthreads();

    // ---- histogram accumulate ----
    for (int i = tid; i < N; i += K2T) {
        float e;
        bool fg;
        if constexpr (FROM_ERR) {
            const float v = err[(size_t)bc * N + i];
            const unsigned int bits = __float_as_uint(v);
            fg = (bits >> 31) != 0u;
            e = __uint_as_float(bits & 0x7fffffffu);
        } else {
            const float* lp = logits + ((size_t)b * C) * N + i;
            float t[C];
            float m = -1e30f;
#pragma unroll
            for (int k = 0; k < C; ++k) { t[k] = lp[(size_t)k * N]; m = fmaxf(m, t[k]); }
            float s = 0.f;
#pragma unroll
            for (int k = 0; k < C; ++k) { t[k] = __expf(t[k] - m); s += t[k]; }
            const float p = t[c] / s;
            fg = (target[(size_t)b * N + i] == c);
            e = fg ? (1.f - p) : p;
        }
        int bkt = (int)(e * (float)NB);
        bkt = bkt < 0 ? 0 : (bkt > NB - 1 ? NB - 1 : bkt);
        if (fg) { atomicAdd(&s_cfg[bkt], 1u); atomicAdd(&s_sfg[bkt], e); }
        else    { atomicAdd(&s_cbg[bkt], 1u); atomicAdd(&s_sbg[bkt], e); }
    }
    __syncthreads();

    // ---- suffix scan over buckets in descending-e order ----
    // pack: high 32 = total count, low 32 = fg count (no cross-field carry:
    // each field sums to <= 131072)
    unsigned long long local = 0ull;
#pragma unroll
    for (int j = 0; j < PER; ++j) {
        const int i = NB - 1 - (tid * PER + j);
        local += ((unsigned long long)(s_cfg[i] + s_cbg[i]) << 32) | (unsigned long long)s_cfg[i];
    }
    s_scan[tid] = local;
    __syncthreads();
    for (int off = 1; off < K2T; off <<= 1) {
        const unsigned long long v = (tid >= off) ? s_scan[tid - off] : 0ull;
        __syncthreads();
        s_scan[tid] += v;
        __syncthreads();
    }
    const unsigned long long total = s_scan[K2T - 1];
    const unsigned long long excl  = s_scan[tid] - local;
    const float G = (float)(unsigned int)(total & 0xffffffffu);

    // ---- per-bucket contributions ----
    float contrib = 0.f, sfg_t = 0.f, sbg_t = 0.f;
    unsigned long long run = excl;
#pragma unroll
    for (int j = 0; j < PER; ++j) {
        const int i = NB - 1 - (tid * PER + j);
        const unsigned int cfg = s_cfg[i];
        const unsigned int cbg = s_cbg[i];
        if ((cfg | cbg) != 0u) {
            if (G > 0.f) {
                const float k0 = (float)(unsigned int)(run >> 32);
                const float F0 = (float)(unsigned int)(run & 0xffffffffu);
                const float U0 = G + k0 - F0;                 // >= G >= 1
                if (cfg) contrib += s_sfg[i] / U0;
                if (cbg) {
                    const float I1 = G - F0 - (float)cfg;
                    contrib += s_sbg[i] * I1 / (U0 * (U0 + (float)cbg));
                }
            }
            sfg_t += s_sfg[i];
            sbg_t += s_sbg[i];
            run += ((unsigned long long)(cfg + cbg) << 32) | (unsigned long long)cfg;
        }
    }
    atomicAdd(&s_red[0], contrib);
    atomicAdd(&s_red[1], sfg_t);
    atomicAdd(&s_red[2], sbg_t);
    __syncthreads();

    if (tid == 0) {
        const float Sfg = s_red[1];
        const float Sbg = s_red[2];
        const bool pres = (G > 0.f);
        // sum(p) = Sbg + G - Sfg ; sum(p*fg) = G - Sfg ; sum(fg) = G
        const float num = 2.f * (G - Sfg) + EPS_V;
        const float den = (Sbg + 2.f * G - Sfg) + EPS_V;
        dice_bc[bc] = num / den;
        loss_bc[bc] = pres ? s_red[0] : 0.f;
        present[bc] = pres ? 1 : 0;
    }
}

// ---------------------------------------------------------------------------
// Kernel 3: combine 160 per-(b,c) scalars + CE into final loss.
// ---------------------------------------------------------------------------
__global__ void finalize_kernel(const double* __restrict__ ce_sum,
                                const float*  __restrict__ loss_bc,
                                const float*  __restrict__ dice_bc,
                                const int*    __restrict__ present,
                                float* __restrict__ out)
{
    __shared__ float l_loss[B * C];
    __shared__ float l_dice[B * C];
    __shared__ int   l_pres[B * C];
    const int tid = threadIdx.x;
    if (tid < B * C) {
        l_loss[tid] = loss_bc[tid];
        l_dice[tid] = dice_bc[tid];
        l_pres[tid] = present[tid];
    }
    __syncthreads();
    if (tid == 0) {
        float lov = 0.f, diceSum = 0.f;
        for (int bb = 0; bb < B; ++bb) {
            float s = 0.f; int np = 0;
            for (int cc = 0; cc < C; ++cc) {
                const int i = bb * C + cc;
                if (l_pres[i]) { s += l_loss[i]; np++; }
                diceSum += l_dice[i];
            }
            const float pb = (np > 0) ? (s / (float)np) : 0.f;
            lov += pb;
        }
        lov /= (float)B;
        const float dice_loss = 1.f - diceSum / (float)(B * C);
        const float ce = (float)(*ce_sum / (double)((size_t)B * N));
        out[0] = ALPHA_W * ce + BETA_W * lov + GAMMA_W * dice_loss;
    }
}

// ---------------------------------------------------------------------------
extern "C" void kernel_launch(void* const* d_in, const int* in_sizes, int n_in,
                              void* d_out, int out_size, void* d_ws, size_t ws_size,
                              hipStream_t stream)
{
    const float* logits = (const float*)d_in[0];
    const int*   target = (const int*)d_in[1];
    float* out = (float*)d_out;

    char* ws = (char*)d_ws;
    double* ce_sum  = (double*)(ws + CE_OFF);
    float*  loss_bc = (float*)(ws + LOSS_OFF);
    float*  dice_bc = (float*)(ws + DICE_OFF);
    int*    present = (int*)(ws + PRES_OFF);
    float*  err     = (float*)(ws + ERR_OFF);

    const bool fast = (ws_size >= ERR_OFF + ERR_BYTES);

    hipMemsetAsync(ws + CE_OFF, 0, sizeof(double), stream);

    if (fast) {
        ce_kernel<true><<<(B * N) / 256, 256, 0, stream>>>(logits, target, ce_sum, err);
        lovasz_kernel<true><<<B * C, K2T, 0, stream>>>(err, logits, target,
                                                       loss_bc, dice_bc, present);
    } else {
        ce_kernel<false><<<(B * N) / 256, 256, 0, stream>>>(logits, target, ce_sum, nullptr);
        lovasz_kernel<false><<<B * C, K2T, 0, stream>>>(nullptr, logits, target,
                                                        loss_bc, dice_bc, present);
    }
    finalize_kernel<<<1, 256, 0, stream>>>(ce_sum, loss_bc, dice_bc, present, out);
}

// Round 2
// 87.521 us; speedup vs baseline: 3.0156x; 3.0156x over previous
//
#include <hip/hip_runtime.h>
#include <hip/hip_fp16.h>
#include <cstdint>
#include <cstddef>

// CombinedLoss: ALPHA*CE + BETA*Lovasz + GAMMA*Dice
// Shapes fixed by setup_inputs(): logits [8,20,131072] f32, target [8,131072] int
#define ALPHA_W 1.0f
#define BETA_W  1.0f
#define GAMMA_W 0.5f
#define EPS_V   1e-6f

constexpr int B = 8;
constexpr int C = 20;
constexpr int N = 131072;    // 2^17
constexpr int LOG2N = 17;

constexpr int NB  = 4096;    // Lovasz buckets; total approx error <~ 1.5/NB
constexpr int SEG = 8;       // histogram segments per (b,c)
constexpr int H2T = 256;     // hist kernel threads
constexpr int CH  = N / SEG; // 16384 elements per segment
constexpr int S3T = 1024;    // scan kernel threads
constexpr int PER3 = NB / S3T;

// workspace layout
constexpr size_t CE_OFF     = 0;                                   // double
constexpr size_t LOSS_OFF   = 64;                                  // float[B*C]
constexpr size_t DICE_OFF   = LOSS_OFF + (size_t)B * C * sizeof(float);
constexpr size_t PRES_OFF   = DICE_OFF + (size_t)B * C * sizeof(float);
constexpr size_t GHIST_OFF  = 4096;                                // u64[B*C*NB]
constexpr size_t GHIST_BYTES= (size_t)B * C * NB * 8;              // 5.24 MB
constexpr size_t ERR_OFF    = GHIST_OFF + GHIST_BYTES;             // u16[B*C*N]
constexpr size_t ERR_BYTES  = (size_t)B * C * N * 2;               // 42 MB

// ---------------------------------------------------------------------------
// Kernel 1: 4 consecutive n per thread (float4). Softmax over C=20, CE via
// block reduce + double atomic; write fp16 error with fg in the sign bit.
// ---------------------------------------------------------------------------
template<bool WRITE_ERR>
__global__ __launch_bounds__(256) void ce4_kernel(const float* __restrict__ logits,
                                                  const int*   __restrict__ target,
                                                  double*      __restrict__ ce_sum,
                                                  unsigned short* __restrict__ err)
{
    const int tid = threadIdx.x;
    const int idx = blockIdx.x * 256 + tid;          // B*N/4 threads total
    const int e0  = idx << 2;                        // flat element base
    const int b   = e0 >> LOG2N;
    const int n   = e0 & (N - 1);
    const float4* lp = (const float4*)(logits + ((size_t)(b * C)) * N + n);
    const int cs = N >> 2;                           // class stride in 4-elem units

    float4 t[C];
    float mx = -1e30f, my = -1e30f, mz = -1e30f, mw = -1e30f;
#pragma unroll
    for (int k = 0; k < C; ++k) {
        t[k] = lp[(size_t)k * cs];
        mx = fmaxf(mx, t[k].x); my = fmaxf(my, t[k].y);
        mz = fmaxf(mz, t[k].z); mw = fmaxf(mw, t[k].w);
    }
    const int4 tg = *(const int4*)(target + e0);
    float sx = 0.f, sy = 0.f, sz = 0.f, sw = 0.f;
    float lx = 0.f, ly = 0.f, lz = 0.f, lw = 0.f;
#pragma unroll
    for (int k = 0; k < C; ++k) {
        if (k == tg.x) lx = t[k].x;
        if (k == tg.y) ly = t[k].y;
        if (k == tg.z) lz = t[k].z;
        if (k == tg.w) lw = t[k].w;
        t[k].x = __expf(t[k].x - mx); sx += t[k].x;
        t[k].y = __expf(t[k].y - my); sy += t[k].y;
        t[k].z = __expf(t[k].z - mz); sz += t[k].z;
        t[k].w = __expf(t[k].w - mw); sw += t[k].w;
    }
    const float nll = (mx + __logf(sx) - lx) + (my + __logf(sy) - ly)
                    + (mz + __logf(sz) - lz) + (mw + __logf(sw) - lw);

    if constexpr (WRITE_ERR) {
        const float ix = 1.f / sx, iy = 1.f / sy, iz = 1.f / sz, iw = 1.f / sw;
        ushort4* ep = (ushort4*)(err + ((size_t)(b * C)) * N + n);
#pragma unroll
        for (int k = 0; k < C; ++k) {
            ushort4 o;
            {
                const bool fg = (k == tg.x); float p = t[k].x * ix;
                float e = fmaxf(fg ? 1.f - p : p, 0.f);
                o.x = (unsigned short)(__half_as_ushort(__float2half(e)) | (fg ? 0x8000u : 0u));
            }
            {
                const bool fg = (k == tg.y); float p = t[k].y * iy;
                float e = fmaxf(fg ? 1.f - p : p, 0.f);
                o.y = (unsigned short)(__half_as_ushort(__float2half(e)) | (fg ? 0x8000u : 0u));
            }
            {
                const bool fg = (k == tg.z); float p = t[k].z * iz;
                float e = fmaxf(fg ? 1.f - p : p, 0.f);
                o.z = (unsigned short)(__half_as_ushort(__float2half(e)) | (fg ? 0x8000u : 0u));
            }
            {
                const bool fg = (k == tg.w); float p = t[k].w * iw;
                float e = fmaxf(fg ? 1.f - p : p, 0.f);
                o.w = (unsigned short)(__half_as_ushort(__float2half(e)) | (fg ? 0x8000u : 0u));
            }
            ep[(size_t)k * cs] = o;
        }
    }

    __shared__ float red[256];
    red[tid] = nll;
    __syncthreads();
    for (int s2 = 128; s2 > 0; s2 >>= 1) {
        if (tid < s2) red[tid] += red[tid + s2];
        __syncthreads();
    }
    if (tid == 0) atomicAdd(ce_sum, (double)red[0]);
}

// ---------------------------------------------------------------------------
// Kernel 2: partial histograms. grid = B*C*SEG. One packed u64 LDS atomic per
// element: (cnt_fg << 32) | cnt_bg. Flush nonzero bins via global u64 atomics.
// ---------------------------------------------------------------------------
__global__ __launch_bounds__(H2T) void hist_kernel(const unsigned short* __restrict__ err,
                                                   unsigned long long* __restrict__ ghist)
{
    __shared__ unsigned long long s_h[NB];
    const int tid = threadIdx.x;
    const int bc  = blockIdx.x / SEG;
    const int seg = blockIdx.x % SEG;
    for (int i = tid; i < NB; i += H2T) s_h[i] = 0ull;
    __syncthreads();

    const uint4* p = (const uint4*)(err + (size_t)bc * N + (size_t)seg * CH);
    for (int i = tid; i < CH / 8; i += H2T) {        // 8 iters: uint4 = 8 u16
        const uint4 v = p[i];
        const unsigned int wd[4] = {v.x, v.y, v.z, v.w};
#pragma unroll
        for (int q = 0; q < 4; ++q) {
#pragma unroll
            for (int hp = 0; hp < 2; ++hp) {
                const unsigned int us = (hp ? (wd[q] >> 16) : wd[q]) & 0xffffu;
                const bool fg = (us & 0x8000u) != 0u;
                const float e = __half2float(__ushort_as_half((unsigned short)(us & 0x7fffu)));
                int bkt = (int)(e * (float)NB);
                bkt = bkt > NB - 1 ? NB - 1 : bkt;
                atomicAdd(&s_h[bkt], fg ? (1ull << 32) : 1ull);
            }
        }
    }
    __syncthreads();

    unsigned long long* g = ghist + (size_t)bc * NB;
    for (int i = tid; i < NB; i += H2T) {
        const unsigned long long v = s_h[i];
        if (v) atomicAdd(&g[i], v);
    }
}

// ---------------------------------------------------------------------------
// Kernel 3: per (b,c): suffix scan of counts in descending-e order, then
// contrib = mid_i * (J_after - J_before), J = 1 - I/U. Dice from cnt*mid sums.
// ---------------------------------------------------------------------------
__global__ __launch_bounds__(S3T) void scan_kernel(const unsigned long long* __restrict__ ghist,
                                                   float* __restrict__ loss_bc,
                                                   float* __restrict__ dice_bc,
                                                   int*   __restrict__ present)
{
    __shared__ unsigned long long s_scan[S3T];
    __shared__ float s_red[3];
    const int bc = blockIdx.x;
    const int tid = threadIdx.x;
    if (tid < 3) s_red[tid] = 0.f;

    const unsigned long long* g = ghist + (size_t)bc * NB;
    unsigned long long h[PER3];
    unsigned long long local = 0ull;
#pragma unroll
    for (int j = 0; j < PER3; ++j) {
        const int i = NB - 1 - (tid * PER3 + j);
        h[j] = g[i];
        local += h[j];
    }
    s_scan[tid] = local;
    __syncthreads();
    for (int off = 1; off < S3T; off <<= 1) {
        const unsigned long long v = (tid >= off) ? s_scan[tid - off] : 0ull;
        __syncthreads();
        s_scan[tid] += v;
        __syncthreads();
    }
    const unsigned long long total = s_scan[S3T - 1];
    const float G = (float)(unsigned int)(total >> 32);
    unsigned long long run = s_scan[tid] - local;     // exclusive prefix (desc order)

    float contrib = 0.f, sfg = 0.f, sbg = 0.f;
#pragma unroll
    for (int j = 0; j < PER3; ++j) {
        const int i = NB - 1 - (tid * PER3 + j);
        const unsigned int cfg = (unsigned int)(h[j] >> 32);
        const unsigned int cbg = (unsigned int)(h[j] & 0xffffffffu);
        if (cfg | cbg) {
            const float mid = ((float)i + 0.5f) / (float)NB;
            if (G > 0.f) {
                const float F0  = (float)(unsigned int)(run >> 32);
                const float bg0 = (float)(unsigned int)(run & 0xffffffffu);
                const float U0 = G + bg0;             // >= G >= 1
                const float I0 = G - F0;
                const float U1 = U0 + (float)cbg;
                const float I1 = I0 - (float)cfg;
                contrib += mid * (I0 / U0 - I1 / U1); // mid * (J1 - J0)
            }
            sfg += (float)cfg * mid;
            sbg += (float)cbg * mid;
            run += h[j];
        }
    }
    atomicAdd(&s_red[0], contrib);
    atomicAdd(&s_red[1], sfg);
    atomicAdd(&s_red[2], sbg);
    __syncthreads();

    if (tid == 0) {
        const float Sfg = s_red[1];
        const float Sbg = s_red[2];
        const bool pres = (G > 0.f);
        // sum(p) = Sbg + G - Sfg ; sum(p*fg) = G - Sfg ; sum(fg) = G
        const float num = 2.f * (G - Sfg) + EPS_V;
        const float den = (Sbg + 2.f * G - Sfg) + EPS_V;
        dice_bc[bc] = num / den;
        loss_bc[bc] = pres ? s_red[0] : 0.f;
        present[bc] = pres ? 1 : 0;
    }
}

// ---------------------------------------------------------------------------
// Fallback (ws too small): one WG per (b,c), recompute softmax, exact v1 path.
// ---------------------------------------------------------------------------
__global__ __launch_bounds__(1024) void lovasz_fb(const float* __restrict__ logits,
                                                  const int*   __restrict__ target,
                                                  float* __restrict__ loss_bc,
                                                  float* __restrict__ dice_bc,
                                                  int*   __restrict__ present)
{
    __shared__ unsigned int s_cfg[NB];
    __shared__ unsigned int s_cbg[NB];
    __shared__ float s_sfg[NB];
    __shared__ float s_sbg[NB];
    __shared__ unsigned long long s_scan[1024];
    __shared__ float s_red[3];

    const int bc = blockIdx.x;
    const int b  = bc / C;
    const int c  = bc % C;
    const int tid = threadIdx.x;

    for (int i = tid; i < NB; i += 1024) {
        s_cfg[i] = 0u; s_cbg[i] = 0u; s_sfg[i] = 0.f; s_sbg[i] = 0.f;
    }
    if (tid < 3) s_red[tid] = 0.f;
    __syncthreads();

    for (int i = tid; i < N; i += 1024) {
        const float* lp = logits + ((size_t)(b * C)) * N + i;
        float t[C];
        float m = -1e30f;
#pragma unroll
        for (int k = 0; k < C; ++k) { t[k] = lp[(size_t)k * N]; m = fmaxf(m, t[k]); }
        float s = 0.f;
#pragma unroll
        for (int k = 0; k < C; ++k) { t[k] = __expf(t[k] - m); s += t[k]; }
        const float p = t[c] / s;
        const bool fg = (target[(size_t)b * N + i] == c);
        const float e = fg ? (1.f - p) : p;
        int bkt = (int)(e * (float)NB);
        bkt = bkt < 0 ? 0 : (bkt > NB - 1 ? NB - 1 : bkt);
        if (fg) { atomicAdd(&s_cfg[bkt], 1u); atomicAdd(&s_sfg[bkt], e); }
        else    { atomicAdd(&s_cbg[bkt], 1u); atomicAdd(&s_sbg[bkt], e); }
    }
    __syncthreads();

    unsigned long long local = 0ull;
#pragma unroll
    for (int j = 0; j < 4; ++j) {
        const int i = NB - 1 - (tid * 4 + j);
        local += ((unsigned long long)(s_cfg[i] + s_cbg[i]) << 32) | (unsigned long long)s_cfg[i];
    }
    s_scan[tid] = local;
    __syncthreads();
    for (int off = 1; off < 1024; off <<= 1) {
        const unsigned long long v = (tid >= off) ? s_scan[tid - off] : 0ull;
        __syncthreads();
        s_scan[tid] += v;
        __syncthreads();
    }
    const unsigned long long total = s_scan[1023];
    const unsigned long long excl  = s_scan[tid] - local;
    const float G = (float)(unsigned int)(total & 0xffffffffu);

    float contrib = 0.f, sfg_t = 0.f, sbg_t = 0.f;
    unsigned long long run = excl;
#pragma unroll
    for (int j = 0; j < 4; ++j) {
        const int i = NB - 1 - (tid * 4 + j);
        const unsigned int cfg = s_cfg[i];
        const unsigned int cbg = s_cbg[i];
        if ((cfg | cbg) != 0u) {
            if (G > 0.f) {
                const float k0 = (float)(unsigned int)(run >> 32);
                const float F0 = (float)(unsigned int)(run & 0xffffffffu);
                const float U0 = G + k0 - F0;
                if (cfg) contrib += s_sfg[i] / U0;
                if (cbg) {
                    const float I1 = G - F0 - (float)cfg;
                    contrib += s_sbg[i] * I1 / (U0 * (U0 + (float)cbg));
                }
            }
            sfg_t += s_sfg[i];
            sbg_t += s_sbg[i];
            run += ((unsigned long long)(cfg + cbg) << 32) | (unsigned long long)cfg;
        }
    }
    atomicAdd(&s_red[0], contrib);
    atomicAdd(&s_red[1], sfg_t);
    atomicAdd(&s_red[2], sbg_t);
    __syncthreads();

    if (tid == 0) {
        const float Sfg = s_red[1];
        const float Sbg = s_red[2];
        const bool pres = (G > 0.f);
        const float num = 2.f * (G - Sfg) + EPS_V;
        const float den = (Sbg + 2.f * G - Sfg) + EPS_V;
        dice_bc[bc] = num / den;
        loss_bc[bc] = pres ? s_red[0] : 0.f;
        present[bc] = pres ? 1 : 0;
    }
}

// ---------------------------------------------------------------------------
// Kernel 4: combine 160 per-(b,c) scalars + CE into final loss.
// ---------------------------------------------------------------------------
__global__ void finalize_kernel(const double* __restrict__ ce_sum,
                                const float*  __restrict__ loss_bc,
                                const float*  __restrict__ dice_bc,
                                const int*    __restrict__ present,
                                float* __restrict__ out)
{
    __shared__ float l_loss[B * C];
    __shared__ float l_dice[B * C];
    __shared__ int   l_pres[B * C];
    const int tid = threadIdx.x;
    if (tid < B * C) {
        l_loss[tid] = loss_bc[tid];
        l_dice[tid] = dice_bc[tid];
        l_pres[tid] = present[tid];
    }
    __syncthreads();
    if (tid == 0) {
        float lov = 0.f, diceSum = 0.f;
        for (int bb = 0; bb < B; ++bb) {
            float s = 0.f; int np = 0;
            for (int cc = 0; cc < C; ++cc) {
                const int i = bb * C + cc;
                if (l_pres[i]) { s += l_loss[i]; np++; }
                diceSum += l_dice[i];
            }
            lov += (np > 0) ? (s / (float)np) : 0.f;
        }
        lov /= (float)B;
        const float dice_loss = 1.f - diceSum / (float)(B * C);
        const float ce = (float)(*ce_sum / (double)((size_t)B * N));
        out[0] = ALPHA_W * ce + BETA_W * lov + GAMMA_W * dice_loss;
    }
}

// ---------------------------------------------------------------------------
extern "C" void kernel_launch(void* const* d_in, const int* in_sizes, int n_in,
                              void* d_out, int out_size, void* d_ws, size_t ws_size,
                              hipStream_t stream)
{
    const float* logits = (const float*)d_in[0];
    const int*   target = (const int*)d_in[1];
    float* out = (float*)d_out;

    char* ws = (char*)d_ws;
    double* ce_sum  = (double*)(ws + CE_OFF);
    float*  loss_bc = (float*)(ws + LOSS_OFF);
    float*  dice_bc = (float*)(ws + DICE_OFF);
    int*    present = (int*)(ws + PRES_OFF);
    unsigned long long* ghist = (unsigned long long*)(ws + GHIST_OFF);
    unsigned short* err = (unsigned short*)(ws + ERR_OFF);

    const bool fast = (ws_size >= ERR_OFF + ERR_BYTES);

    hipMemsetAsync(ws + CE_OFF, 0, sizeof(double), stream);

    if (fast) {
        hipMemsetAsync(ws + GHIST_OFF, 0, GHIST_BYTES, stream);
        ce4_kernel<true><<<(B * N / 4) / 256, 256, 0, stream>>>(logits, target, ce_sum, err);
        hist_kernel<<<B * C * SEG, H2T, 0, stream>>>(err, ghist);
        scan_kernel<<<B * C, S3T, 0, stream>>>(ghist, loss_bc, dice_bc, present);
    } else {
        ce4_kernel<false><<<(B * N / 4) / 256, 256, 0, stream>>>(logits, target, ce_sum, nullptr);
        lovasz_fb<<<B * C, 1024, 0, stream>>>(logits, target, loss_bc, dice_bc, present);
    }
    finalize_kernel<<<1, 256, 0, stream>>>(ce_sum, loss_bc, dice_bc, present, out);
}

// Round 3
// 75.561 us; speedup vs baseline: 3.4929x; 1.1583x over previous
//
#include <hip/hip_runtime.h>
#include <cstdint>
#include <cstddef>

// CombinedLoss: ALPHA*CE + BETA*Lovasz + GAMMA*Dice
// Shapes fixed by setup_inputs(): logits [8,20,131072] f32, target [8,131072] int
#define ALPHA_W 1.0f
#define BETA_W  1.0f
#define GAMMA_W 0.5f
#define EPS_V   1e-6f

constexpr int B = 8;
constexpr int C = 20;
constexpr int N = 131072;    // 2^17
constexpr int LOG2N = 17;

constexpr int NB  = 4096;    // Lovasz buckets; total approx error <~ 1.5/NB
constexpr int SEG = 8;       // histogram segments per (b,c)
constexpr int H2T = 256;     // hist kernel threads
constexpr int CH  = N / SEG; // 16384 elements per segment
constexpr int S3T = 1024;    // scan kernel threads
constexpr int PER3 = NB / S3T;

constexpr int CE_BLOCKS = (B * N / 4) / 256;   // 1024

// workspace layout
constexpr size_t LOSS_OFF   = 0;                                   // float[B*C]
constexpr size_t DICE_OFF   = LOSS_OFF + (size_t)B * C * sizeof(float);
constexpr size_t PRES_OFF   = DICE_OFF + (size_t)B * C * sizeof(float);
constexpr size_t CEPART_OFF = 2048;                                // float[CE_BLOCKS]
constexpr size_t GHIST_OFF  = 8192;                                // u64[B*C*NB]
constexpr size_t GHIST_BYTES= (size_t)B * C * NB * 8;              // 5.24 MB
constexpr size_t ERR_OFF    = GHIST_OFF + GHIST_BYTES;             // u16[B*C*N]
constexpr size_t ERR_BYTES  = (size_t)B * C * N * 2;               // 42 MB

// ---------------------------------------------------------------------------
// Kernel 1: 4 consecutive n per thread (float4). Softmax over C=20.
// CE partial per block (plain store, no atomic, no memset needed).
// err word = (fg << 15) | bucket(e)  (12-bit bucket, computed from f32).
// Also zeroes ghist (runs before hist_kernel in stream order).
// ---------------------------------------------------------------------------
template<bool WRITE_ERR>
__global__ __launch_bounds__(256) void ce4_kernel(const float* __restrict__ logits,
                                                  const int*   __restrict__ target,
                                                  float*       __restrict__ ce_part,
                                                  unsigned short* __restrict__ err,
                                                  unsigned long long* __restrict__ ghist)
{
    const int tid = threadIdx.x;
    const int idx = blockIdx.x * 256 + tid;          // B*N/4 threads total

    if constexpr (WRITE_ERR) {
        // zero ghist: 655360 u64 across 262144 threads -> <=3 each
        for (size_t i = idx; i < (size_t)B * C * NB; i += (size_t)CE_BLOCKS * 256)
            ghist[i] = 0ull;
    }

    const int e0  = idx << 2;                        // flat element base
    const int b   = e0 >> LOG2N;
    const int n   = e0 & (N - 1);
    const float4* lp = (const float4*)(logits + ((size_t)(b * C)) * N + n);
    const int cs = N >> 2;                           // class stride in 4-elem units

    float4 t[C];
    float mx = -1e30f, my = -1e30f, mz = -1e30f, mw = -1e30f;
#pragma unroll
    for (int k = 0; k < C; ++k) {
        t[k] = lp[(size_t)k * cs];
        mx = fmaxf(mx, t[k].x); my = fmaxf(my, t[k].y);
        mz = fmaxf(mz, t[k].z); mw = fmaxf(mw, t[k].w);
    }
    const int4 tg = *(const int4*)(target + e0);
    float sx = 0.f, sy = 0.f, sz = 0.f, sw = 0.f;
    float lx = 0.f, ly = 0.f, lz = 0.f, lw = 0.f;
#pragma unroll
    for (int k = 0; k < C; ++k) {
        if (k == tg.x) lx = t[k].x;
        if (k == tg.y) ly = t[k].y;
        if (k == tg.z) lz = t[k].z;
        if (k == tg.w) lw = t[k].w;
        t[k].x = __expf(t[k].x - mx); sx += t[k].x;
        t[k].y = __expf(t[k].y - my); sy += t[k].y;
        t[k].z = __expf(t[k].z - mz); sz += t[k].z;
        t[k].w = __expf(t[k].w - mw); sw += t[k].w;
    }
    const float nll = (mx + __logf(sx) - lx) + (my + __logf(sy) - ly)
                    + (mz + __logf(sz) - lz) + (mw + __logf(sw) - lw);

    if constexpr (WRITE_ERR) {
        const float ix = 1.f / sx, iy = 1.f / sy, iz = 1.f / sz, iw = 1.f / sw;
        ushort4* ep = (ushort4*)(err + ((size_t)(b * C)) * N + n);
#pragma unroll
        for (int k = 0; k < C; ++k) {
            ushort4 o;
            {
                const bool fg = (k == tg.x);
                const float e = fmaxf(fg ? 1.f - t[k].x * ix : t[k].x * ix, 0.f);
                int bk = (int)(e * (float)NB); bk = bk > NB - 1 ? NB - 1 : bk;
                o.x = (unsigned short)((fg ? 0x8000u : 0u) | (unsigned)bk);
            }
            {
                const bool fg = (k == tg.y);
                const float e = fmaxf(fg ? 1.f - t[k].y * iy : t[k].y * iy, 0.f);
                int bk = (int)(e * (float)NB); bk = bk > NB - 1 ? NB - 1 : bk;
                o.y = (unsigned short)((fg ? 0x8000u : 0u) | (unsigned)bk);
            }
            {
                const bool fg = (k == tg.z);
                const float e = fmaxf(fg ? 1.f - t[k].z * iz : t[k].z * iz, 0.f);
                int bk = (int)(e * (float)NB); bk = bk > NB - 1 ? NB - 1 : bk;
                o.z = (unsigned short)((fg ? 0x8000u : 0u) | (unsigned)bk);
            }
            {
                const bool fg = (k == tg.w);
                const float e = fmaxf(fg ? 1.f - t[k].w * iw : t[k].w * iw, 0.f);
                int bk = (int)(e * (float)NB); bk = bk > NB - 1 ? NB - 1 : bk;
                o.w = (unsigned short)((fg ? 0x8000u : 0u) | (unsigned)bk);
            }
            ep[(size_t)k * cs] = o;
        }
    }

    __shared__ float red[256];
    red[tid] = nll;
    __syncthreads();
    for (int s2 = 128; s2 > 0; s2 >>= 1) {
        if (tid < s2) red[tid] += red[tid + s2];
        __syncthreads();
    }
    if (tid == 0) ce_part[blockIdx.x] = red[0];
}

// ---------------------------------------------------------------------------
// Kernel 2: partial histograms. grid = B*C*SEG. Pure-integer inner loop: one
// packed u64 LDS atomic per element: (cnt_fg << 32) | cnt_bg. Flush nonzero
// bins via global u64 atomics (ghist pre-zeroed by ce4).
// ---------------------------------------------------------------------------
__global__ __launch_bounds__(H2T) void hist_kernel(const unsigned short* __restrict__ err,
                                                   unsigned long long* __restrict__ ghist)
{
    __shared__ unsigned long long s_h[NB];
    const int tid = threadIdx.x;
    const int bc  = blockIdx.x / SEG;
    const int seg = blockIdx.x % SEG;
    for (int i = tid; i < NB; i += H2T) s_h[i] = 0ull;
    __syncthreads();

    const uint4* p = (const uint4*)(err + (size_t)bc * N + (size_t)seg * CH);
    for (int i = tid; i < CH / 8; i += H2T) {        // 8 iters: uint4 = 8 u16
        const uint4 v = p[i];
        const unsigned int wd[4] = {v.x, v.y, v.z, v.w};
#pragma unroll
        for (int q = 0; q < 4; ++q) {
#pragma unroll
            for (int hp = 0; hp < 2; ++hp) {
                const unsigned int us = (hp ? (wd[q] >> 16) : wd[q]) & 0xffffu;
                const int bkt = (int)(us & 0x0fffu);
                atomicAdd(&s_h[bkt], (us & 0x8000u) ? (1ull << 32) : 1ull);
            }
        }
    }
    __syncthreads();

    unsigned long long* g = ghist + (size_t)bc * NB;
    for (int i = tid; i < NB; i += H2T) {
        const unsigned long long v = s_h[i];
        if (v) atomicAdd(&g[i], v);
    }
}

// ---------------------------------------------------------------------------
// Kernel 3: per (b,c): suffix scan of counts in descending-e order, then
// contrib = mid_i * (J_after - J_before), J = 1 - I/U. Dice from cnt*mid sums.
// ---------------------------------------------------------------------------
__global__ __launch_bounds__(S3T) void scan_kernel(const unsigned long long* __restrict__ ghist,
                                                   float* __restrict__ loss_bc,
                                                   float* __restrict__ dice_bc,
                                                   int*   __restrict__ present)
{
    __shared__ unsigned long long s_scan[S3T];
    __shared__ float s_red[3];
    const int bc = blockIdx.x;
    const int tid = threadIdx.x;
    if (tid < 3) s_red[tid] = 0.f;

    const unsigned long long* g = ghist + (size_t)bc * NB;
    unsigned long long h[PER3];
    unsigned long long local = 0ull;
#pragma unroll
    for (int j = 0; j < PER3; ++j) {
        const int i = NB - 1 - (tid * PER3 + j);
        h[j] = g[i];
        local += h[j];
    }
    s_scan[tid] = local;
    __syncthreads();
    for (int off = 1; off < S3T; off <<= 1) {
        const unsigned long long v = (tid >= off) ? s_scan[tid - off] : 0ull;
        __syncthreads();
        s_scan[tid] += v;
        __syncthreads();
    }
    const unsigned long long total = s_scan[S3T - 1];
    const float G = (float)(unsigned int)(total >> 32);
    unsigned long long run = s_scan[tid] - local;     // exclusive prefix (desc order)

    float contrib = 0.f, sfg = 0.f, sbg = 0.f;
#pragma unroll
    for (int j = 0; j < PER3; ++j) {
        const int i = NB - 1 - (tid * PER3 + j);
        const unsigned int cfg = (unsigned int)(h[j] >> 32);
        const unsigned int cbg = (unsigned int)(h[j] & 0xffffffffu);
        if (cfg | cbg) {
            const float mid = ((float)i + 0.5f) / (float)NB;
            if (G > 0.f) {
                const float F0  = (float)(unsigned int)(run >> 32);
                const float bg0 = (float)(unsigned int)(run & 0xffffffffu);
                const float U0 = G + bg0;             // >= G >= 1
                const float I0 = G - F0;
                const float U1 = U0 + (float)cbg;
                const float I1 = I0 - (float)cfg;
                contrib += mid * (I0 / U0 - I1 / U1); // mid * (J1 - J0)
            }
            sfg += (float)cfg * mid;
            sbg += (float)cbg * mid;
            run += h[j];
        }
    }
    atomicAdd(&s_red[0], contrib);
    atomicAdd(&s_red[1], sfg);
    atomicAdd(&s_red[2], sbg);
    __syncthreads();

    if (tid == 0) {
        const float Sfg = s_red[1];
        const float Sbg = s_red[2];
        const bool pres = (G > 0.f);
        // sum(p) = Sbg + G - Sfg ; sum(p*fg) = G - Sfg ; sum(fg) = G
        const float num = 2.f * (G - Sfg) + EPS_V;
        const float den = (Sbg + 2.f * G - Sfg) + EPS_V;
        dice_bc[bc] = num / den;
        loss_bc[bc] = pres ? s_red[0] : 0.f;
        present[bc] = pres ? 1 : 0;
    }
}

// ---------------------------------------------------------------------------
// Fallback (ws too small): one WG per (b,c), recompute softmax, exact path.
// ---------------------------------------------------------------------------
__global__ __launch_bounds__(1024) void lovasz_fb(const float* __restrict__ logits,
                                                  const int*   __restrict__ target,
                                                  float* __restrict__ loss_bc,
                                                  float* __restrict__ dice_bc,
                                                  int*   __restrict__ present)
{
    __shared__ unsigned int s_cfg[NB];
    __shared__ unsigned int s_cbg[NB];
    __shared__ float s_sfg[NB];
    __shared__ float s_sbg[NB];
    __shared__ unsigned long long s_scan[1024];
    __shared__ float s_red[3];

    const int bc = blockIdx.x;
    const int b  = bc / C;
    const int c  = bc % C;
    const int tid = threadIdx.x;

    for (int i = tid; i < NB; i += 1024) {
        s_cfg[i] = 0u; s_cbg[i] = 0u; s_sfg[i] = 0.f; s_sbg[i] = 0.f;
    }
    if (tid < 3) s_red[tid] = 0.f;
    __syncthreads();

    for (int i = tid; i < N; i += 1024) {
        const float* lp = logits + ((size_t)(b * C)) * N + i;
        float t[C];
        float m = -1e30f;
#pragma unroll
        for (int k = 0; k < C; ++k) { t[k] = lp[(size_t)k * N]; m = fmaxf(m, t[k]); }
        float s = 0.f;
#pragma unroll
        for (int k = 0; k < C; ++k) { t[k] = __expf(t[k] - m); s += t[k]; }
        const float p = t[c] / s;
        const bool fg = (target[(size_t)b * N + i] == c);
        const float e = fg ? (1.f - p) : p;
        int bkt = (int)(e * (float)NB);
        bkt = bkt < 0 ? 0 : (bkt > NB - 1 ? NB - 1 : bkt);
        if (fg) { atomicAdd(&s_cfg[bkt], 1u); atomicAdd(&s_sfg[bkt], e); }
        else    { atomicAdd(&s_cbg[bkt], 1u); atomicAdd(&s_sbg[bkt], e); }
    }
    __syncthreads();

    unsigned long long local = 0ull;
#pragma unroll
    for (int j = 0; j < 4; ++j) {
        const int i = NB - 1 - (tid * 4 + j);
        local += ((unsigned long long)(s_cfg[i] + s_cbg[i]) << 32) | (unsigned long long)s_cfg[i];
    }
    s_scan[tid] = local;
    __syncthreads();
    for (int off = 1; off < 1024; off <<= 1) {
        const unsigned long long v = (tid >= off) ? s_scan[tid - off] : 0ull;
        __syncthreads();
        s_scan[tid] += v;
        __syncthreads();
    }
    const unsigned long long total = s_scan[1023];
    const unsigned long long excl  = s_scan[tid] - local;
    const float G = (float)(unsigned int)(total & 0xffffffffu);

    float contrib = 0.f, sfg_t = 0.f, sbg_t = 0.f;
    unsigned long long run = excl;
#pragma unroll
    for (int j = 0; j < 4; ++j) {
        const int i = NB - 1 - (tid * 4 + j);
        const unsigned int cfg = s_cfg[i];
        const unsigned int cbg = s_cbg[i];
        if ((cfg | cbg) != 0u) {
            if (G > 0.f) {
                const float k0 = (float)(unsigned int)(run >> 32);
                const float F0 = (float)(unsigned int)(run & 0xffffffffu);
                const float U0 = G + k0 - F0;
                if (cfg) contrib += s_sfg[i] / U0;
                if (cbg) {
                    const float I1 = G - F0 - (float)cfg;
                    contrib += s_sbg[i] * I1 / (U0 * (U0 + (float)cbg));
                }
            }
            sfg_t += s_sfg[i];
            sbg_t += s_sbg[i];
            run += ((unsigned long long)(cfg + cbg) << 32) | (unsigned long long)cfg;
        }
    }
    atomicAdd(&s_red[0], contrib);
    atomicAdd(&s_red[1], sfg_t);
    atomicAdd(&s_red[2], sbg_t);
    __syncthreads();

    if (tid == 0) {
        const float Sfg = s_red[1];
        const float Sbg = s_red[2];
        const bool pres = (G > 0.f);
        const float num = 2.f * (G - Sfg) + EPS_V;
        const float den = (Sbg + 2.f * G - Sfg) + EPS_V;
        dice_bc[bc] = num / den;
        loss_bc[bc] = pres ? s_red[0] : 0.f;
        present[bc] = pres ? 1 : 0;
    }
}

// ---------------------------------------------------------------------------
// Kernel 4: combine 160 per-(b,c) scalars + 1024 CE partials into final loss.
// ---------------------------------------------------------------------------
__global__ __launch_bounds__(256) void finalize_kernel(const float* __restrict__ ce_part,
                                                       const float* __restrict__ loss_bc,
                                                       const float* __restrict__ dice_bc,
                                                       const int*   __restrict__ present,
                                                       float* __restrict__ out)
{
    __shared__ float l_loss[B * C];
    __shared__ float l_dice[B * C];
    __shared__ int   l_pres[B * C];
    __shared__ float cred[256];
    const int tid = threadIdx.x;
    if (tid < B * C) {
        l_loss[tid] = loss_bc[tid];
        l_dice[tid] = dice_bc[tid];
        l_pres[tid] = present[tid];
    }
    float cs = 0.f;
    for (int i = tid; i < CE_BLOCKS; i += 256) cs += ce_part[i];
    cred[tid] = cs;
    __syncthreads();
    for (int s2 = 128; s2 > 0; s2 >>= 1) {
        if (tid < s2) cred[tid] += cred[tid + s2];
        __syncthreads();
    }
    if (tid == 0) {
        float lov = 0.f, diceSum = 0.f;
        for (int bb = 0; bb < B; ++bb) {
            float s = 0.f; int np = 0;
            for (int cc = 0; cc < C; ++cc) {
                const int i = bb * C + cc;
                if (l_pres[i]) { s += l_loss[i]; np++; }
                diceSum += l_dice[i];
            }
            lov += (np > 0) ? (s / (float)np) : 0.f;
        }
        lov /= (float)B;
        const float dice_loss = 1.f - diceSum / (float)(B * C);
        const float ce = cred[0] / (float)((size_t)B * N);
        out[0] = ALPHA_W * ce + BETA_W * lov + GAMMA_W * dice_loss;
    }
}

// ---------------------------------------------------------------------------
extern "C" void kernel_launch(void* const* d_in, const int* in_sizes, int n_in,
                              void* d_out, int out_size, void* d_ws, size_t ws_size,
                              hipStream_t stream)
{
    const float* logits = (const float*)d_in[0];
    const int*   target = (const int*)d_in[1];
    float* out = (float*)d_out;

    char* ws = (char*)d_ws;
    float*  loss_bc = (float*)(ws + LOSS_OFF);
    float*  dice_bc = (float*)(ws + DICE_OFF);
    int*    present = (int*)(ws + PRES_OFF);
    float*  ce_part = (float*)(ws + CEPART_OFF);
    unsigned long long* ghist = (unsigned long long*)(ws + GHIST_OFF);
    unsigned short* err = (unsigned short*)(ws + ERR_OFF);

    const bool fast = (ws_size >= ERR_OFF + ERR_BYTES);

    if (fast) {
        ce4_kernel<true><<<CE_BLOCKS, 256, 0, stream>>>(logits, target, ce_part, err, ghist);
        hist_kernel<<<B * C * SEG, H2T, 0, stream>>>(err, ghist);
        scan_kernel<<<B * C, S3T, 0, stream>>>(ghist, loss_bc, dice_bc, present);
    } else {
        ce4_kernel<false><<<CE_BLOCKS, 256, 0, stream>>>(logits, target, ce_part, nullptr, nullptr);
        lovasz_fb<<<B * C, 1024, 0, stream>>>(logits, target, loss_bc, dice_bc, present);
    }
    finalize_kernel<<<1, 256, 0, stream>>>(ce_part, loss_bc, dice_bc, present, out);
}

// Round 4
// 60.256 us; speedup vs baseline: 4.3801x; 1.2540x over previous
//
#include <hip/hip_runtime.h>
#include <cstdint>
#include <cstddef>

// CombinedLoss: ALPHA*CE + BETA*Lovasz + GAMMA*Dice
// Shapes fixed by setup_inputs(): logits [8,20,131072] f32, target [8,131072] int
#define ALPHA_W 1.0f
#define BETA_W  1.0f
#define GAMMA_W 0.5f
#define EPS_V   1e-6f

constexpr int B = 8;
constexpr int C = 20;
constexpr int N = 131072;    // 2^17
constexpr int LOG2N = 17;

constexpr int NB  = 4096;    // Lovasz buckets; total approx error <~ 1.5/NB
constexpr int HS_T = 1024;   // histscan threads
constexpr int PER  = NB / HS_T;  // 4 bins per thread in the scan phase

constexpr int CE_BLOCKS = (B * N / 4) / 256;   // 1024

// workspace layout
constexpr size_t LOSS_OFF   = 0;                                   // float[B*C]
constexpr size_t DICE_OFF   = LOSS_OFF + (size_t)B * C * sizeof(float);
constexpr size_t PRES_OFF   = DICE_OFF + (size_t)B * C * sizeof(float);
constexpr size_t CEPART_OFF = 2048;                                // float[CE_BLOCKS]
constexpr size_t ERR_OFF    = 8192;                                // u16[B*C*N]
constexpr size_t ERR_BYTES  = (size_t)B * C * N * 2;               // 42 MB

// ---------------------------------------------------------------------------
// Kernel 1: 4 consecutive n per thread (float4). Softmax over C=20.
// CE partial per block (plain store, no atomic, no memset needed).
// err word = (fg << 15) | bucket(e)  (12-bit bucket, computed from f32).
// ---------------------------------------------------------------------------
template<bool WRITE_ERR>
__global__ __launch_bounds__(256) void ce4_kernel(const float* __restrict__ logits,
                                                  const int*   __restrict__ target,
                                                  float*       __restrict__ ce_part,
                                                  unsigned short* __restrict__ err)
{
    const int tid = threadIdx.x;
    const int idx = blockIdx.x * 256 + tid;          // B*N/4 threads total
    const int e0  = idx << 2;                        // flat element base
    const int b   = e0 >> LOG2N;
    const int n   = e0 & (N - 1);
    const float4* lp = (const float4*)(logits + ((size_t)(b * C)) * N + n);
    const int cs = N >> 2;                           // class stride in 4-elem units

    float4 t[C];
    float mx = -1e30f, my = -1e30f, mz = -1e30f, mw = -1e30f;
#pragma unroll
    for (int k = 0; k < C; ++k) {
        t[k] = lp[(size_t)k * cs];
        mx = fmaxf(mx, t[k].x); my = fmaxf(my, t[k].y);
        mz = fmaxf(mz, t[k].z); mw = fmaxf(mw, t[k].w);
    }
    const int4 tg = *(const int4*)(target + e0);
    float sx = 0.f, sy = 0.f, sz = 0.f, sw = 0.f;
    float lx = 0.f, ly = 0.f, lz = 0.f, lw = 0.f;
#pragma unroll
    for (int k = 0; k < C; ++k) {
        if (k == tg.x) lx = t[k].x;
        if (k == tg.y) ly = t[k].y;
        if (k == tg.z) lz = t[k].z;
        if (k == tg.w) lw = t[k].w;
        t[k].x = __expf(t[k].x - mx); sx += t[k].x;
        t[k].y = __expf(t[k].y - my); sy += t[k].y;
        t[k].z = __expf(t[k].z - mz); sz += t[k].z;
        t[k].w = __expf(t[k].w - mw); sw += t[k].w;
    }
    const float nll = (mx + __logf(sx) - lx) + (my + __logf(sy) - ly)
                    + (mz + __logf(sz) - lz) + (mw + __logf(sw) - lw);

    if constexpr (WRITE_ERR) {
        const float ix = 1.f / sx, iy = 1.f / sy, iz = 1.f / sz, iw = 1.f / sw;
        ushort4* ep = (ushort4*)(err + ((size_t)(b * C)) * N + n);
#pragma unroll
        for (int k = 0; k < C; ++k) {
            ushort4 o;
            {
                const bool fg = (k == tg.x);
                const float e = fmaxf(fg ? 1.f - t[k].x * ix : t[k].x * ix, 0.f);
                int bk = (int)(e * (float)NB); bk = bk > NB - 1 ? NB - 1 : bk;
                o.x = (unsigned short)((fg ? 0x8000u : 0u) | (unsigned)bk);
            }
            {
                const bool fg = (k == tg.y);
                const float e = fmaxf(fg ? 1.f - t[k].y * iy : t[k].y * iy, 0.f);
                int bk = (int)(e * (float)NB); bk = bk > NB - 1 ? NB - 1 : bk;
                o.y = (unsigned short)((fg ? 0x8000u : 0u) | (unsigned)bk);
            }
            {
                const bool fg = (k == tg.z);
                const float e = fmaxf(fg ? 1.f - t[k].z * iz : t[k].z * iz, 0.f);
                int bk = (int)(e * (float)NB); bk = bk > NB - 1 ? NB - 1 : bk;
                o.z = (unsigned short)((fg ? 0x8000u : 0u) | (unsigned)bk);
            }
            {
                const bool fg = (k == tg.w);
                const float e = fmaxf(fg ? 1.f - t[k].w * iw : t[k].w * iw, 0.f);
                int bk = (int)(e * (float)NB); bk = bk > NB - 1 ? NB - 1 : bk;
                o.w = (unsigned short)((fg ? 0x8000u : 0u) | (unsigned)bk);
            }
            ep[(size_t)k * cs] = o;
        }
    }

    __shared__ float red[256];
    red[tid] = nll;
    __syncthreads();
    for (int s2 = 128; s2 > 0; s2 >>= 1) {
        if (tid < s2) red[tid] += red[tid + s2];
        __syncthreads();
    }
    if (tid == 0) ce_part[blockIdx.x] = red[0];
}

// ---------------------------------------------------------------------------
// Kernel 2 (fused hist+scan): one block of 1024 per (b,c). Histogram the
// whole row into two parity-split LDS histograms (packed u64 counts:
// (cnt_fg << 32) | cnt_bg), then suffix-scan in descending-e order via a
// two-level wave-shuffle scan, and apply the closed-form Lovasz gradient:
//   contrib = mid_i * (J_after - J_before), J = I/U terms from prefix counts.
// Dice numerator/denominator from the same cnt*mid sums. No global atomics.
// ---------------------------------------------------------------------------
__global__ __launch_bounds__(HS_T) void histscan_kernel(const unsigned short* __restrict__ err,
                                                        float* __restrict__ loss_bc,
                                                        float* __restrict__ dice_bc,
                                                        int*   __restrict__ present)
{
    __shared__ unsigned long long s_h[2][NB];      // 64 KB
    __shared__ unsigned long long s_wexcl[16];
    __shared__ unsigned long long s_total;
    __shared__ float s_red[3];

    const int bc   = blockIdx.x;
    const int tid  = threadIdx.x;
    const int lane = tid & 63;
    const int wid  = tid >> 6;

    {
        unsigned long long* hflat = &s_h[0][0];
        for (int i = tid; i < 2 * NB; i += HS_T) hflat[i] = 0ull;
    }
    if (tid < 3) s_red[tid] = 0.f;
    __syncthreads();

    // ---- histogram accumulate (pure integer) ----
    unsigned long long* hh = s_h[wid & 1];
    const uint4* p = (const uint4*)(err + (size_t)bc * N);
    for (int i = tid; i < N / 8; i += HS_T) {      // 16 iters, 8 u16 per uint4
        const uint4 v = p[i];
        const unsigned int wd[4] = {v.x, v.y, v.z, v.w};
#pragma unroll
        for (int q = 0; q < 4; ++q) {
#pragma unroll
            for (int hp = 0; hp < 2; ++hp) {
                const unsigned int us = (hp ? (wd[q] >> 16) : wd[q]) & 0xffffu;
                atomicAdd(&hh[us & 0x0fffu], (us & 0x8000u) ? (1ull << 32) : 1ull);
            }
        }
    }
    __syncthreads();

    // ---- per-thread load of PER bins in descending-e order, merged ----
    unsigned long long h[PER];
    unsigned long long local = 0ull;
#pragma unroll
    for (int j = 0; j < PER; ++j) {
        const int i = NB - 1 - (tid * PER + j);
        h[j] = s_h[0][i] + s_h[1][i];
        local += h[j];
    }

    // ---- two-level exclusive scan (wave shuffle + 16-partial scan) ----
    unsigned long long x = local;
#pragma unroll
    for (int off = 1; off < 64; off <<= 1) {
        const unsigned long long y = __shfl_up(x, off);
        if (lane >= off) x += y;
    }
    __shared__ unsigned long long s_wtot[16];
    if (lane == 63) s_wtot[wid] = x;
    __syncthreads();
    if (wid == 0 && lane < 16) {
        const unsigned long long w = s_wtot[lane];
        unsigned long long xx = w;
#pragma unroll
        for (int off = 1; off < 16; off <<= 1) {
            const unsigned long long y = __shfl_up(xx, off);
            if (lane >= off) xx += y;
        }
        s_wexcl[lane] = xx - w;
        if (lane == 15) s_total = xx;
    }
    __syncthreads();

    const unsigned long long total = s_total;
    const float G = (float)(unsigned int)(total >> 32);
    unsigned long long run = s_wexcl[wid] + (x - local);   // exclusive prefix

    // ---- per-bucket contributions ----
    float contrib = 0.f, sfg = 0.f, sbg = 0.f;
#pragma unroll
    for (int j = 0; j < PER; ++j) {
        const int i = NB - 1 - (tid * PER + j);
        const unsigned int cfg = (unsigned int)(h[j] >> 32);
        const unsigned int cbg = (unsigned int)(h[j] & 0xffffffffu);
        if (cfg | cbg) {
            const float mid = ((float)i + 0.5f) / (float)NB;
            if (G > 0.f) {
                const float F0  = (float)(unsigned int)(run >> 32);
                const float bg0 = (float)(unsigned int)(run & 0xffffffffu);
                const float U0 = G + bg0;             // >= G >= 1
                const float I0 = G - F0;
                const float U1 = U0 + (float)cbg;
                const float I1 = I0 - (float)cfg;
                contrib += mid * (I0 / U0 - I1 / U1); // mid * (J1 - J0)
            }
            sfg += (float)cfg * mid;
            sbg += (float)cbg * mid;
            run += h[j];
        }
    }
    atomicAdd(&s_red[0], contrib);
    atomicAdd(&s_red[1], sfg);
    atomicAdd(&s_red[2], sbg);
    __syncthreads();

    if (tid == 0) {
        const float Sfg = s_red[1];
        const float Sbg = s_red[2];
        const bool pres = (G > 0.f);
        // sum(p) = Sbg + G - Sfg ; sum(p*fg) = G - Sfg ; sum(fg) = G
        const float num = 2.f * (G - Sfg) + EPS_V;
        const float den = (Sbg + 2.f * G - Sfg) + EPS_V;
        dice_bc[bc] = num / den;
        loss_bc[bc] = pres ? s_red[0] : 0.f;
        present[bc] = pres ? 1 : 0;
    }
}

// ---------------------------------------------------------------------------
// Fallback (ws too small): one WG per (b,c), recompute softmax, exact path.
// ---------------------------------------------------------------------------
__global__ __launch_bounds__(1024) void lovasz_fb(const float* __restrict__ logits,
                                                  const int*   __restrict__ target,
                                                  float* __restrict__ loss_bc,
                                                  float* __restrict__ dice_bc,
                                                  int*   __restrict__ present)
{
    __shared__ unsigned int s_cfg[NB];
    __shared__ unsigned int s_cbg[NB];
    __shared__ float s_sfg[NB];
    __shared__ float s_sbg[NB];
    __shared__ unsigned long long s_scan[1024];
    __shared__ float s_red[3];

    const int bc = blockIdx.x;
    const int b  = bc / C;
    const int c  = bc % C;
    const int tid = threadIdx.x;

    for (int i = tid; i < NB; i += 1024) {
        s_cfg[i] = 0u; s_cbg[i] = 0u; s_sfg[i] = 0.f; s_sbg[i] = 0.f;
    }
    if (tid < 3) s_red[tid] = 0.f;
    __syncthreads();

    for (int i = tid; i < N; i += 1024) {
        const float* lp = logits + ((size_t)(b * C)) * N + i;
        float t[C];
        float m = -1e30f;
#pragma unroll
        for (int k = 0; k < C; ++k) { t[k] = lp[(size_t)k * N]; m = fmaxf(m, t[k]); }
        float s = 0.f;
#pragma unroll
        for (int k = 0; k < C; ++k) { t[k] = __expf(t[k] - m); s += t[k]; }
        const float p = t[c] / s;
        const bool fg = (target[(size_t)b * N + i] == c);
        const float e = fg ? (1.f - p) : p;
        int bkt = (int)(e * (float)NB);
        bkt = bkt < 0 ? 0 : (bkt > NB - 1 ? NB - 1 : bkt);
        if (fg) { atomicAdd(&s_cfg[bkt], 1u); atomicAdd(&s_sfg[bkt], e); }
        else    { atomicAdd(&s_cbg[bkt], 1u); atomicAdd(&s_sbg[bkt], e); }
    }
    __syncthreads();

    unsigned long long local = 0ull;
#pragma unroll
    for (int j = 0; j < 4; ++j) {
        const int i = NB - 1 - (tid * 4 + j);
        local += ((unsigned long long)(s_cfg[i] + s_cbg[i]) << 32) | (unsigned long long)s_cfg[i];
    }
    s_scan[tid] = local;
    __syncthreads();
    for (int off = 1; off < 1024; off <<= 1) {
        const unsigned long long v = (tid >= off) ? s_scan[tid - off] : 0ull;
        __syncthreads();
        s_scan[tid] += v;
        __syncthreads();
    }
    const unsigned long long total = s_scan[1023];
    const unsigned long long excl  = s_scan[tid] - local;
    const float G = (float)(unsigned int)(total & 0xffffffffu);

    float contrib = 0.f, sfg_t = 0.f, sbg_t = 0.f;
    unsigned long long run = excl;
#pragma unroll
    for (int j = 0; j < 4; ++j) {
        const int i = NB - 1 - (tid * 4 + j);
        const unsigned int cfg = s_cfg[i];
        const unsigned int cbg = s_cbg[i];
        if ((cfg | cbg) != 0u) {
            if (G > 0.f) {
                const float k0 = (float)(unsigned int)(run >> 32);
                const float F0 = (float)(unsigned int)(run & 0xffffffffu);
                const float U0 = G + k0 - F0;
                if (cfg) contrib += s_sfg[i] / U0;
                if (cbg) {
                    const float I1 = G - F0 - (float)cfg;
                    contrib += s_sbg[i] * I1 / (U0 * (U0 + (float)cbg));
                }
            }
            sfg_t += s_sfg[i];
            sbg_t += s_sbg[i];
            run += ((unsigned long long)(cfg + cbg) << 32) | (unsigned long long)cfg;
        }
    }
    atomicAdd(&s_red[0], contrib);
    atomicAdd(&s_red[1], sfg_t);
    atomicAdd(&s_red[2], sbg_t);
    __syncthreads();

    if (tid == 0) {
        const float Sfg = s_red[1];
        const float Sbg = s_red[2];
        const bool pres = (G > 0.f);
        const float num = 2.f * (G - Sfg) + EPS_V;
        const float den = (Sbg + 2.f * G - Sfg) + EPS_V;
        dice_bc[bc] = num / den;
        loss_bc[bc] = pres ? s_red[0] : 0.f;
        present[bc] = pres ? 1 : 0;
    }
}

// ---------------------------------------------------------------------------
// Kernel 3: combine 160 per-(b,c) scalars + 1024 CE partials into final loss.
// ---------------------------------------------------------------------------
__global__ __launch_bounds__(256) void finalize_kernel(const float* __restrict__ ce_part,
                                                       const float* __restrict__ loss_bc,
                                                       const float* __restrict__ dice_bc,
                                                       const int*   __restrict__ present,
                                                       float* __restrict__ out)
{
    __shared__ float l_loss[B * C];
    __shared__ float l_dice[B * C];
    __shared__ int   l_pres[B * C];
    __shared__ float cred[256];
    const int tid = threadIdx.x;
    if (tid < B * C) {
        l_loss[tid] = loss_bc[tid];
        l_dice[tid] = dice_bc[tid];
        l_pres[tid] = present[tid];
    }
    float cs = 0.f;
    for (int i = tid; i < CE_BLOCKS; i += 256) cs += ce_part[i];
    cred[tid] = cs;
    __syncthreads();
    for (int s2 = 128; s2 > 0; s2 >>= 1) {
        if (tid < s2) cred[tid] += cred[tid + s2];
        __syncthreads();
    }
    if (tid == 0) {
        float lov = 0.f, diceSum = 0.f;
        for (int bb = 0; bb < B; ++bb) {
            float s = 0.f; int np = 0;
            for (int cc = 0; cc < C; ++cc) {
                const int i = bb * C + cc;
                if (l_pres[i]) { s += l_loss[i]; np++; }
                diceSum += l_dice[i];
            }
            lov += (np > 0) ? (s / (float)np) : 0.f;
        }
        lov /= (float)B;
        const float dice_loss = 1.f - diceSum / (float)(B * C);
        const float ce = cred[0] / (float)((size_t)B * N);
        out[0] = ALPHA_W * ce + BETA_W * lov + GAMMA_W * dice_loss;
    }
}

// ---------------------------------------------------------------------------
extern "C" void kernel_launch(void* const* d_in, const int* in_sizes, int n_in,
                              void* d_out, int out_size, void* d_ws, size_t ws_size,
                              hipStream_t stream)
{
    const float* logits = (const float*)d_in[0];
    const int*   target = (const int*)d_in[1];
    float* out = (float*)d_out;

    char* ws = (char*)d_ws;
    float*  loss_bc = (float*)(ws + LOSS_OFF);
    float*  dice_bc = (float*)(ws + DICE_OFF);
    int*    present = (int*)(ws + PRES_OFF);
    float*  ce_part = (float*)(ws + CEPART_OFF);
    unsigned short* err = (unsigned short*)(ws + ERR_OFF);

    const bool fast = (ws_size >= ERR_OFF + ERR_BYTES);

    if (fast) {
        ce4_kernel<true><<<CE_BLOCKS, 256, 0, stream>>>(logits, target, ce_part, err);
        histscan_kernel<<<B * C, HS_T, 0, stream>>>(err, loss_bc, dice_bc, present);
    } else {
        ce4_kernel<false><<<CE_BLOCKS, 256, 0, stream>>>(logits, target, ce_part, nullptr);
        lovasz_fb<<<B * C, 1024, 0, stream>>>(logits, target, loss_bc, dice_bc, present);
    }
    finalize_kernel<<<1, 256, 0, stream>>>(ce_part, loss_bc, dice_bc, present, out);
}

// Round 5
// 46.913 us; speedup vs baseline: 5.6260x; 1.2844x over previous
//
#include <hip/hip_runtime.h>
#include <cstdint>
#include <cstddef>

// CombinedLoss: ALPHA*CE + BETA*Lovasz + GAMMA*Dice
// Shapes fixed by setup_inputs(): logits [8,20,131072] f32, target [8,131072] int
#define ALPHA_W 1.0f
#define BETA_W  1.0f
#define GAMMA_W 0.5f
#define EPS_V   1e-6f

constexpr int B = 8;
constexpr int C = 20;
constexpr int N = 131072;        // 2^17
constexpr int LOG2N = 17;

constexpr int NB    = 256;       // Lovasz buckets; |error| <= ~1/(2*NB) + dice eps
constexpr int T1    = 256;       // fused kernel threads
constexpr int CHUNK = 2048;      // n-elements per fused block
constexpr int CPB   = N / CHUNK; // 64 chunks per b
constexpr int GRID1 = B * CPB;   // 512 blocks
constexpr int HBINS = C * NB;    // 5120 bins per block (all classes)

constexpr int NBFB = 4096;       // fallback bucket count (exact-ish path)

// workspace layout
constexpr size_t LOSS_OFF   = 0;                                   // float[B*C]
constexpr size_t DICE_OFF   = LOSS_OFF + (size_t)B * C * sizeof(float);
constexpr size_t PRES_OFF   = DICE_OFF + (size_t)B * C * sizeof(float);
constexpr size_t CEPART_OFF = 2048;                                // float[GRID1]
constexpr size_t PART_OFF   = 8192;                                // u32[GRID1*HBINS]
constexpr size_t PART_BYTES = (size_t)GRID1 * HBINS * 4;           // 10.49 MB
constexpr size_t WS_NEED    = PART_OFF + PART_BYTES;

// ---------------------------------------------------------------------------
// Kernel 1 (fused): one block = 2048 consecutive n of one b, 8 elems/thread
// in two float4 groups (g*1024 + tid*4 keeps lanes coalesced). Softmax over
// C=20, CE partial per block (plain store). Histogram ALL classes into LDS:
// hist[c][bin] u32 packed (fg<<16 | bg); flush with plain coalesced stores.
// No global atomics, fully deterministic.
// ---------------------------------------------------------------------------
template<bool WH>
__global__ __launch_bounds__(T1) void fused_kernel(const float* __restrict__ logits,
                                                   const int*   __restrict__ target,
                                                   float*       __restrict__ ce_part,
                                                   unsigned*    __restrict__ partial)
{
    __shared__ unsigned s_hist[HBINS];     // 20 KB
    __shared__ float red[T1];

    const int tid   = threadIdx.x;
    const int b     = blockIdx.x / CPB;
    const int chunk = blockIdx.x % CPB;

    if constexpr (WH) {
        for (int i = tid; i < HBINS; i += T1) s_hist[i] = 0u;
        __syncthreads();
    }

    const size_t lbase = (size_t)b * C * N;
    const int cs = N >> 2;                 // class stride in float4 units
    float nll_acc = 0.f;

#pragma unroll
    for (int g = 0; g < 2; ++g) {
        const int n = chunk * CHUNK + g * 1024 + tid * 4;
        const float4* lp = (const float4*)(logits + lbase + n);

        float4 t[C];
        float mx = -1e30f, my = -1e30f, mz = -1e30f, mw = -1e30f;
#pragma unroll
        for (int k = 0; k < C; ++k) {
            t[k] = lp[(size_t)k * cs];
            mx = fmaxf(mx, t[k].x); my = fmaxf(my, t[k].y);
            mz = fmaxf(mz, t[k].z); mw = fmaxf(mw, t[k].w);
        }
        const int4 tg = *(const int4*)(target + (size_t)b * N + n);
        float sx = 0.f, sy = 0.f, sz = 0.f, sw = 0.f;
        float lx = 0.f, ly = 0.f, lz = 0.f, lw = 0.f;
#pragma unroll
        for (int k = 0; k < C; ++k) {
            if (k == tg.x) lx = t[k].x;
            if (k == tg.y) ly = t[k].y;
            if (k == tg.z) lz = t[k].z;
            if (k == tg.w) lw = t[k].w;
            t[k].x = __expf(t[k].x - mx); sx += t[k].x;
            t[k].y = __expf(t[k].y - my); sy += t[k].y;
            t[k].z = __expf(t[k].z - mz); sz += t[k].z;
            t[k].w = __expf(t[k].w - mw); sw += t[k].w;
        }
        nll_acc += (mx + __logf(sx) - lx) + (my + __logf(sy) - ly)
                 + (mz + __logf(sz) - lz) + (mw + __logf(sw) - lw);

        if constexpr (WH) {
            const float ix = 1.f / sx, iy = 1.f / sy, iz = 1.f / sz, iw = 1.f / sw;
#pragma unroll
            for (int k = 0; k < C; ++k) {
                {
                    const bool fg = (k == tg.x);
                    const float e = fmaxf(fg ? 1.f - t[k].x * ix : t[k].x * ix, 0.f);
                    int bk = (int)(e * (float)NB); bk = bk > NB - 1 ? NB - 1 : bk;
                    atomicAdd(&s_hist[k * NB + bk], fg ? 0x10000u : 1u);
                }
                {
                    const bool fg = (k == tg.y);
                    const float e = fmaxf(fg ? 1.f - t[k].y * iy : t[k].y * iy, 0.f);
                    int bk = (int)(e * (float)NB); bk = bk > NB - 1 ? NB - 1 : bk;
                    atomicAdd(&s_hist[k * NB + bk], fg ? 0x10000u : 1u);
                }
                {
                    const bool fg = (k == tg.z);
                    const float e = fmaxf(fg ? 1.f - t[k].z * iz : t[k].z * iz, 0.f);
                    int bk = (int)(e * (float)NB); bk = bk > NB - 1 ? NB - 1 : bk;
                    atomicAdd(&s_hist[k * NB + bk], fg ? 0x10000u : 1u);
                }
                {
                    const bool fg = (k == tg.w);
                    const float e = fmaxf(fg ? 1.f - t[k].w * iw : t[k].w * iw, 0.f);
                    int bk = (int)(e * (float)NB); bk = bk > NB - 1 ? NB - 1 : bk;
                    atomicAdd(&s_hist[k * NB + bk], fg ? 0x10000u : 1u);
                }
            }
        }
    }

    if constexpr (WH) {
        __syncthreads();
        unsigned* gp = partial + (size_t)blockIdx.x * HBINS;
        for (int i = tid; i < HBINS; i += T1) gp[i] = s_hist[i];
    }

    red[tid] = nll_acc;
    __syncthreads();
    for (int s2 = 128; s2 > 0; s2 >>= 1) {
        if (tid < s2) red[tid] += red[tid + s2];
        __syncthreads();
    }
    if (tid == 0) ce_part[blockIdx.x] = red[0];
}

// ---------------------------------------------------------------------------
// Kernel 2: one 256-thread block per (b,c). Thread t owns bin (NB-1-t);
// sums 64 chunk-partials (coalesced), shuffle-scans the packed
// (fg<<32 | bg) counts in descending-e order, applies closed-form Lovasz:
//   contrib = mid * (I0/U0 - I1/U1)  per nonzero bin,
// and Dice from cnt*mid sums.
// ---------------------------------------------------------------------------
__global__ __launch_bounds__(NB) void scan_kernel(const unsigned* __restrict__ partial,
                                                  float* __restrict__ loss_bc,
                                                  float* __restrict__ dice_bc,
                                                  int*   __restrict__ present)
{
    __shared__ unsigned long long s_wtot[4];
    __shared__ float s_red[3];

    const int bc   = blockIdx.x;
    const int b    = bc / C;
    const int c    = bc % C;
    const int tid  = threadIdx.x;            // 0..255
    const int lane = tid & 63;
    const int wid  = tid >> 6;
    const int bin  = NB - 1 - tid;           // ascending tid = descending e

    if (tid < 3) s_red[tid] = 0.f;

    unsigned cfg = 0u, cbg = 0u;
    const unsigned* base = partial + ((size_t)b * CPB) * HBINS + c * NB + bin;
    for (int ch = 0; ch < CPB; ++ch) {
        const unsigned v = base[(size_t)ch * HBINS];
        cfg += v >> 16;
        cbg += v & 0xffffu;
    }
    const unsigned long long mine = ((unsigned long long)cfg << 32) | (unsigned long long)cbg;

    // intra-wave inclusive scan
    unsigned long long x = mine;
#pragma unroll
    for (int off = 1; off < 64; off <<= 1) {
        const unsigned long long y = __shfl_up(x, off);
        if (lane >= off) x += y;
    }
    if (lane == 63) s_wtot[wid] = x;
    __syncthreads();
    unsigned long long wexcl = 0ull, total = 0ull;
#pragma unroll
    for (int w = 0; w < 4; ++w) {
        const unsigned long long v = s_wtot[w];
        if (w < wid) wexcl += v;
        total += v;
    }
    unsigned long long run = wexcl + (x - mine);   // exclusive prefix
    const float G = (float)(unsigned int)(total >> 32);

    float contrib = 0.f, sfg = 0.f, sbg = 0.f;
    if (cfg | cbg) {
        const float mid = ((float)bin + 0.5f) / (float)NB;
        if (G > 0.f) {
            const float F0  = (float)(unsigned int)(run >> 32);
            const float bg0 = (float)(unsigned int)(run & 0xffffffffu);
            const float U0 = G + bg0;              // >= G >= 1
            const float I0 = G - F0;
            const float U1 = U0 + (float)cbg;
            const float I1 = I0 - (float)cfg;
            contrib = mid * (I0 / U0 - I1 / U1);   // mid * (J1 - J0)
        }
        sfg = (float)cfg * mid;
        sbg = (float)cbg * mid;
    }
    // wave-level reduce, then one LDS atomic per wave per quantity
#pragma unroll
    for (int off = 32; off > 0; off >>= 1) {
        contrib += __shfl_down(contrib, off);
        sfg     += __shfl_down(sfg, off);
        sbg     += __shfl_down(sbg, off);
    }
    if (lane == 0) {
        atomicAdd(&s_red[0], contrib);
        atomicAdd(&s_red[1], sfg);
        atomicAdd(&s_red[2], sbg);
    }
    __syncthreads();

    if (tid == 0) {
        const float Sfg = s_red[1];
        const float Sbg = s_red[2];
        const bool pres = (G > 0.f);
        // sum(p) = Sbg + G - Sfg ; sum(p*fg) = G - Sfg ; sum(fg) = G
        const float num = 2.f * (G - Sfg) + EPS_V;
        const float den = (Sbg + 2.f * G - Sfg) + EPS_V;
        dice_bc[bc] = num / den;
        loss_bc[bc] = pres ? s_red[0] : 0.f;
        present[bc] = pres ? 1 : 0;
    }
}

// ---------------------------------------------------------------------------
// Fallback (ws too small): one WG per (b,c), recompute softmax, fine-bucket
// exact-sum path (matches r1-verified implementation).
// ---------------------------------------------------------------------------
__global__ __launch_bounds__(1024) void lovasz_fb(const float* __restrict__ logits,
                                                  const int*   __restrict__ target,
                                                  float* __restrict__ loss_bc,
                                                  float* __restrict__ dice_bc,
                                                  int*   __restrict__ present)
{
    __shared__ unsigned int s_cfg[NBFB];
    __shared__ unsigned int s_cbg[NBFB];
    __shared__ float s_sfg[NBFB];
    __shared__ float s_sbg[NBFB];
    __shared__ unsigned long long s_scan[1024];
    __shared__ float s_red[3];

    const int bc = blockIdx.x;
    const int b  = bc / C;
    const int c  = bc % C;
    const int tid = threadIdx.x;

    for (int i = tid; i < NBFB; i += 1024) {
        s_cfg[i] = 0u; s_cbg[i] = 0u; s_sfg[i] = 0.f; s_sbg[i] = 0.f;
    }
    if (tid < 3) s_red[tid] = 0.f;
    __syncthreads();

    for (int i = tid; i < N; i += 1024) {
        const float* lp = logits + ((size_t)(b * C)) * N + i;
        float t[C];
        float m = -1e30f;
#pragma unroll
        for (int k = 0; k < C; ++k) { t[k] = lp[(size_t)k * N]; m = fmaxf(m, t[k]); }
        float s = 0.f;
#pragma unroll
        for (int k = 0; k < C; ++k) { t[k] = __expf(t[k] - m); s += t[k]; }
        const float p = t[c] / s;
        const bool fg = (target[(size_t)b * N + i] == c);
        const float e = fg ? (1.f - p) : p;
        int bkt = (int)(e * (float)NBFB);
        bkt = bkt < 0 ? 0 : (bkt > NBFB - 1 ? NBFB - 1 : bkt);
        if (fg) { atomicAdd(&s_cfg[bkt], 1u); atomicAdd(&s_sfg[bkt], e); }
        else    { atomicAdd(&s_cbg[bkt], 1u); atomicAdd(&s_sbg[bkt], e); }
    }
    __syncthreads();

    unsigned long long local = 0ull;
#pragma unroll
    for (int j = 0; j < 4; ++j) {
        const int i = NBFB - 1 - (tid * 4 + j);
        local += ((unsigned long long)(s_cfg[i] + s_cbg[i]) << 32) | (unsigned long long)s_cfg[i];
    }
    s_scan[tid] = local;
    __syncthreads();
    for (int off = 1; off < 1024; off <<= 1) {
        const unsigned long long v = (tid >= off) ? s_scan[tid - off] : 0ull;
        __syncthreads();
        s_scan[tid] += v;
        __syncthreads();
    }
    const unsigned long long total = s_scan[1023];
    const unsigned long long excl  = s_scan[tid] - local;
    const float G = (float)(unsigned int)(total & 0xffffffffu);

    float contrib = 0.f, sfg_t = 0.f, sbg_t = 0.f;
    unsigned long long run = excl;
#pragma unroll
    for (int j = 0; j < 4; ++j) {
        const int i = NBFB - 1 - (tid * 4 + j);
        const unsigned int cfg = s_cfg[i];
        const unsigned int cbg = s_cbg[i];
        if ((cfg | cbg) != 0u) {
            if (G > 0.f) {
                const float k0 = (float)(unsigned int)(run >> 32);
                const float F0 = (float)(unsigned int)(run & 0xffffffffu);
                const float U0 = G + k0 - F0;
                if (cfg) contrib += s_sfg[i] / U0;
                if (cbg) {
                    const float I1 = G - F0 - (float)cfg;
                    contrib += s_sbg[i] * I1 / (U0 * (U0 + (float)cbg));
                }
            }
            sfg_t += s_sfg[i];
            sbg_t += s_sbg[i];
            run += ((unsigned long long)(cfg + cbg) << 32) | (unsigned long long)cfg;
        }
    }
    atomicAdd(&s_red[0], contrib);
    atomicAdd(&s_red[1], sfg_t);
    atomicAdd(&s_red[2], sbg_t);
    __syncthreads();

    if (tid == 0) {
        const float Sfg = s_red[1];
        const float Sbg = s_red[2];
        const bool pres = (G > 0.f);
        const float num = 2.f * (G - Sfg) + EPS_V;
        const float den = (Sbg + 2.f * G - Sfg) + EPS_V;
        dice_bc[bc] = num / den;
        loss_bc[bc] = pres ? s_red[0] : 0.f;
        present[bc] = pres ? 1 : 0;
    }
}

// ---------------------------------------------------------------------------
// Kernel 3: combine 160 per-(b,c) scalars + GRID1 CE partials into final loss.
// ---------------------------------------------------------------------------
__global__ __launch_bounds__(256) void finalize_kernel(const float* __restrict__ ce_part,
                                                       const float* __restrict__ loss_bc,
                                                       const float* __restrict__ dice_bc,
                                                       const int*   __restrict__ present,
                                                       float* __restrict__ out)
{
    __shared__ float l_loss[B * C];
    __shared__ float l_dice[B * C];
    __shared__ int   l_pres[B * C];
    __shared__ float cred[256];
    const int tid = threadIdx.x;
    if (tid < B * C) {
        l_loss[tid] = loss_bc[tid];
        l_dice[tid] = dice_bc[tid];
        l_pres[tid] = present[tid];
    }
    float cs = 0.f;
    for (int i = tid; i < GRID1; i += 256) cs += ce_part[i];
    cred[tid] = cs;
    __syncthreads();
    for (int s2 = 128; s2 > 0; s2 >>= 1) {
        if (tid < s2) cred[tid] += cred[tid + s2];
        __syncthreads();
    }
    if (tid == 0) {
        float lov = 0.f, diceSum = 0.f;
        for (int bb = 0; bb < B; ++bb) {
            float s = 0.f; int np = 0;
            for (int cc = 0; cc < C; ++cc) {
                const int i = bb * C + cc;
                if (l_pres[i]) { s += l_loss[i]; np++; }
                diceSum += l_dice[i];
            }
            lov += (np > 0) ? (s / (float)np) : 0.f;
        }
        lov /= (float)B;
        const float dice_loss = 1.f - diceSum / (float)(B * C);
        const float ce = cred[0] / (float)((size_t)B * N);
        out[0] = ALPHA_W * ce + BETA_W * lov + GAMMA_W * dice_loss;
    }
}

// ---------------------------------------------------------------------------
extern "C" void kernel_launch(void* const* d_in, const int* in_sizes, int n_in,
                              void* d_out, int out_size, void* d_ws, size_t ws_size,
                              hipStream_t stream)
{
    const float* logits = (const float*)d_in[0];
    const int*   target = (const int*)d_in[1];
    float* out = (float*)d_out;

    char* ws = (char*)d_ws;
    float*    loss_bc = (float*)(ws + LOSS_OFF);
    float*    dice_bc = (float*)(ws + DICE_OFF);
    int*      present = (int*)(ws + PRES_OFF);
    float*    ce_part = (float*)(ws + CEPART_OFF);
    unsigned* partial = (unsigned*)(ws + PART_OFF);

    const bool fast = (ws_size >= WS_NEED);

    if (fast) {
        fused_kernel<true><<<GRID1, T1, 0, stream>>>(logits, target, ce_part, partial);
        scan_kernel<<<B * C, NB, 0, stream>>>(partial, loss_bc, dice_bc, present);
    } else {
        fused_kernel<false><<<GRID1, T1, 0, stream>>>(logits, target, ce_part, nullptr);
        lovasz_fb<<<B * C, 1024, 0, stream>>>(logits, target, loss_bc, dice_bc, present);
    }
    finalize_kernel<<<1, 256, 0, stream>>>(ce_part, loss_bc, dice_bc, present, out);
}